// Round 3
// baseline (674.409 us; speedup 1.0000x reference)
//
#include <hip/hip_runtime.h>
#include <hip/hip_bf16.h>

#define EPSBN 1e-5f
#define NGRAPH 512

struct f4 { float x, y, z, w; };
__device__ inline void f4add(f4& a, const float4& b) {
    a.x += b.x; a.y += b.y; a.z += b.z; a.w += b.w;
}
__device__ inline float f4c(const float4& v, int i) {
    return i == 0 ? v.x : i == 1 ? v.y : i == 2 ? v.z : v.w;
}

// ---------------------------------------------------------------------------
// CSR build step 1: histogram of dst
// ---------------------------------------------------------------------------
__global__ void __launch_bounds__(256) k_hist(
    const int* __restrict__ dst, int* __restrict__ hist, int E)
{
    for (int e = blockIdx.x * 256 + threadIdx.x; e < E; e += gridDim.x * 256)
        atomicAdd(&hist[dst[e]], 1);
}

// ---------------------------------------------------------------------------
// CSR build step 2: single-block exclusive prefix scan of hist
// ---------------------------------------------------------------------------
__global__ void __launch_bounds__(1024) k_scan(
    const int* __restrict__ hist, int* __restrict__ row_off,
    int* __restrict__ cursor, int N)
{
    __shared__ int part[1024];
    const int t = threadIdx.x;
    const int C = (N + 1023) / 1024;
    const int c0 = t * C;
    const int c1 = min(c0 + C, N);
    int s = 0;
    for (int i = c0; i < c1; i++) s += hist[i];
    part[t] = s;
    __syncthreads();
    for (int off = 1; off < 1024; off <<= 1) {
        int v = (t >= off) ? part[t - off] : 0;
        __syncthreads();
        part[t] += v;
        __syncthreads();
    }
    int run = part[t] - s;  // exclusive prefix
    for (int i = c0; i < c1; i++) {
        row_off[i] = run;
        cursor[i] = run;
        run += hist[i];
    }
    if (t == 0) row_off[N] = part[1023];
}

// ---------------------------------------------------------------------------
// CSR build step 3: scatter src ids into per-dst slots
// ---------------------------------------------------------------------------
__global__ void __launch_bounds__(256) k_scatter(
    const int* __restrict__ src, const int* __restrict__ dst,
    int* __restrict__ cursor, int* __restrict__ csr, int E)
{
    for (int e = blockIdx.x * 256 + threadIdx.x; e < E; e += gridDim.x * 256) {
        int d = dst[e];
        int p = atomicAdd(&cursor[d], 1);
        csr[p] = src[e];
    }
}

// ---------------------------------------------------------------------------
// Gather-aggregate: agg[i][:] = sum over neighbors s of feat[s][:]
// ---------------------------------------------------------------------------
template <int F>
__global__ void __launch_bounds__(256) k_gather(
    const float* __restrict__ feat, const int* __restrict__ row_off,
    const int* __restrict__ csr, float* __restrict__ agg, int N)
{
    constexpr int LPR = F / 4;        // lanes per row
    constexpr int RPB = 256 / LPR;    // rows per block
    const int lane = threadIdx.x % LPR;
    const int rloc = threadIdx.x / LPR;
    for (int row = blockIdx.x * RPB + rloc; row < N; row += gridDim.x * RPB) {
        const int s0 = row_off[row];
        const int s1 = row_off[row + 1];
        f4 acc0 = {0, 0, 0, 0}, acc1 = {0, 0, 0, 0};
        int p = s0;
        for (; p + 1 < s1; p += 2) {
            int sA = csr[p];
            int sB = csr[p + 1];
            f4add(acc0, *(const float4*)&feat[(long long)sA * F + lane * 4]);
            f4add(acc1, *(const float4*)&feat[(long long)sB * F + lane * 4]);
        }
        if (p < s1) {
            int sA = csr[p];
            f4add(acc0, *(const float4*)&feat[(long long)sA * F + lane * 4]);
        }
        float4 out;
        out.x = acc0.x + acc1.x; out.y = acc0.y + acc1.y;
        out.z = acc0.z + acc1.z; out.w = acc0.w + acc1.w;
        *(float4*)&agg[(long long)row * F + lane * 4] = out;
    }
}

// ---------------------------------------------------------------------------
// Register-tiled fused GEMM.
//   out = [relu]( (xin_eff @ W) * (SCALEX? applied on X load: invc) 
//                 + HASBASE * (SCALEB? invc:1) * base + FINAL*bias )
//   xin_eff = AFFINE ? xin*a+c : xin.  FINAL also accumulates col sum/sumsq.
// Tile: 64 rows x FOUT cols per block. 256 threads, each computes 4 x TC
// (TC = FOUT/16) outputs in registers. base may alias out (in-place).
// ---------------------------------------------------------------------------
template <int FIN, int FOUT, bool AFFINE, bool SCALEX, bool HASBASE,
          bool SCALEB, bool FINAL>
__global__ void __launch_bounds__(256) k_gemm(
    const float* __restrict__ xin,
    const float* __restrict__ a_in, const float* __restrict__ c_in,
    const float* __restrict__ W,
    const float* __restrict__ bias,
    const float* base,                 // may alias out
    const int* __restrict__ row_off,
    float* out,
    float* __restrict__ s_out, float* __restrict__ q_out,
    int N)
{
    constexpr int TC = FOUT / 16;   // 8, 4, or 2
    constexpr int LD = FIN + 4;     // padded LDS stride (row offset = 16B mult)
    __shared__ float sX[64 * LD];
    __shared__ float sW[FIN * FOUT];
    __shared__ float sinvc[64];
    __shared__ float red[256];

    const int tid = threadIdx.x;
    const int ct = tid & 15;
    const int rt = tid >> 4;
    const int tile0 = blockIdx.x * 64;
    const int j0 = ct * TC;
    const int r0 = rt * 4;

    // stage W (reused for whole tile)
    #pragma unroll
    for (int q = tid; q < FIN * FOUT / 4; q += 256)
        *(float4*)&sW[q * 4] = *(const float4*)&W[q * 4];

    // per-row inverse neighbor count (for epilogue SCALEB use)
    if constexpr (SCALEB) {
        if (tid < 64) {
            int row = tile0 + tid;
            float c = 1.f;
            if (row < N) c = (float)max(row_off[row + 1] - row_off[row], 1);
            sinvc[tid] = 1.f / c;
        }
    }

    // stage X tile (affine / row-scale applied on load)
    {
        constexpr int XV = 64 * FIN / 4;
        #pragma unroll
        for (int q = tid; q < XV; q += 256) {
            int row = q / (FIN / 4);
            int kq = (q % (FIN / 4)) * 4;
            int grow = tile0 + row;
            float4 v = {0.f, 0.f, 0.f, 0.f};
            if (grow < N) {
                v = *(const float4*)&xin[(long long)grow * FIN + kq];
                if constexpr (AFFINE) {
                    float4 av = *(const float4*)&a_in[kq];
                    float4 cv = *(const float4*)&c_in[kq];
                    v.x = v.x * av.x + cv.x; v.y = v.y * av.y + cv.y;
                    v.z = v.z * av.z + cv.z; v.w = v.w * av.w + cv.w;
                }
                if constexpr (SCALEX) {
                    int cnt = row_off[grow + 1] - row_off[grow];
                    float ic = 1.f / (float)max(cnt, 1);
                    v.x *= ic; v.y *= ic; v.z *= ic; v.w *= ic;
                }
            }
            *(float4*)&sX[row * LD + kq] = v;
        }
    }
    __syncthreads();

    // main K loop
    float acc[4][TC];
    #pragma unroll
    for (int r = 0; r < 4; r++)
        #pragma unroll
        for (int c = 0; c < TC; c++) acc[r][c] = 0.f;

    for (int k = 0; k < FIN; k += 4) {
        float4 xv[4];
        #pragma unroll
        for (int r = 0; r < 4; r++)
            xv[r] = *(const float4*)&sX[(r0 + r) * LD + k];
        #pragma unroll
        for (int kk = 0; kk < 4; kk++) {
            float w[TC];
            if constexpr (TC == 8) {
                float4 w0 = *(const float4*)&sW[(k + kk) * FOUT + j0];
                float4 w1 = *(const float4*)&sW[(k + kk) * FOUT + j0 + 4];
                w[0] = w0.x; w[1] = w0.y; w[2] = w0.z; w[3] = w0.w;
                w[4] = w1.x; w[5] = w1.y; w[6] = w1.z; w[7] = w1.w;
            } else if constexpr (TC == 4) {
                float4 w0 = *(const float4*)&sW[(k + kk) * FOUT + j0];
                w[0] = w0.x; w[1] = w0.y; w[2] = w0.z; w[3] = w0.w;
            } else {
                float2 w0 = *(const float2*)&sW[(k + kk) * FOUT + j0];
                w[0] = w0.x; w[1] = w0.y;
            }
            #pragma unroll
            for (int r = 0; r < 4; r++) {
                float xk = f4c(xv[r], kk);
                #pragma unroll
                for (int c = 0; c < TC; c++)
                    acc[r][c] = fmaf(xk, w[c], acc[r][c]);
            }
        }
    }

    // epilogue
    float ssum[TC], ssq[TC];
    #pragma unroll
    for (int c = 0; c < TC; c++) { ssum[c] = 0.f; ssq[c] = 0.f; }

    #pragma unroll
    for (int r = 0; r < 4; r++) {
        int grow = tile0 + r0 + r;
        if (grow < N) {
            long long o = (long long)grow * FOUT + j0;
            float v[TC];
            #pragma unroll
            for (int c = 0; c < TC; c++) v[c] = acc[r][c];
            if constexpr (HASBASE) {
                float s = 1.f;
                if constexpr (SCALEB) s = sinvc[r0 + r];
                if constexpr (TC >= 4) {
                    #pragma unroll
                    for (int c4 = 0; c4 < TC; c4 += 4) {
                        float4 b4 = *(const float4*)&base[o + c4];
                        v[c4 + 0] = fmaf(s, b4.x, v[c4 + 0]);
                        v[c4 + 1] = fmaf(s, b4.y, v[c4 + 1]);
                        v[c4 + 2] = fmaf(s, b4.z, v[c4 + 2]);
                        v[c4 + 3] = fmaf(s, b4.w, v[c4 + 3]);
                    }
                } else {
                    float2 b2 = *(const float2*)&base[o];
                    v[0] = fmaf(s, b2.x, v[0]);
                    v[1] = fmaf(s, b2.y, v[1]);
                }
            }
            if constexpr (FINAL) {
                #pragma unroll
                for (int c = 0; c < TC; c++) {
                    v[c] = fmaxf(v[c] + bias[j0 + c], 0.f);
                    ssum[c] += v[c];
                    ssq[c] += v[c] * v[c];
                }
            }
            if constexpr (TC >= 4) {
                #pragma unroll
                for (int c4 = 0; c4 < TC; c4 += 4) {
                    float4 o4 = make_float4(v[c4], v[c4 + 1], v[c4 + 2], v[c4 + 3]);
                    *(float4*)&out[o + c4] = o4;
                }
            } else {
                float2 o2 = make_float2(v[0], v[1]);
                *(float2*)&out[o] = o2;
            }
        }
    }

    // BN stats: block-reduce, one atomic per column per block
    if constexpr (FINAL) {
        #pragma unroll
        for (int c = 0; c < TC; c++) {
            __syncthreads();
            red[tid] = ssum[c];
            __syncthreads();
            if (rt == 0) {
                float tot = 0.f;
                for (int r = 0; r < 16; r++) tot += red[r * 16 + ct];
                atomicAdd(&s_out[j0 + c], tot);
            }
            __syncthreads();
            red[tid] = ssq[c];
            __syncthreads();
            if (rt == 0) {
                float tot = 0.f;
                for (int r = 0; r < 16; r++) tot += red[r * 16 + ct];
                atomicAdd(&q_out[j0 + c], tot);
            }
        }
    }
}

// ---------------------------------------------------------------------------
// BN affine finalize: a = g / sqrt(var+eps), c = be - mu*a
// ---------------------------------------------------------------------------
__global__ void k_finalize(const float* __restrict__ s, const float* __restrict__ q,
                           const float* __restrict__ g, const float* __restrict__ be,
                           float* __restrict__ a, float* __restrict__ c,
                           int F, float invN)
{
    int j = threadIdx.x;
    if (j < F) {
        float mu = s[j] * invN;
        float var = q[j] * invN - mu * mu;
        float aj = g[j] / sqrtf(var + EPSBN);
        a[j] = aj;
        c[j] = be[j] - mu * aj;
    }
}

// ---------------------------------------------------------------------------
// pooled[batch[i]][j] += t3[i][j]*a[j] + c[j]
// ---------------------------------------------------------------------------
__global__ void __launch_bounds__(256) k_pool(
    const float* __restrict__ t3, const float* __restrict__ a,
    const float* __restrict__ c, const int* __restrict__ batch,
    float* __restrict__ pooled, int N)
{
    long long gid = (long long)blockIdx.x * 256 + threadIdx.x;
    int i = (int)(gid >> 5);
    int j = (int)(gid & 31);
    if (i >= N) return;
    int g = batch[i];
    float v = t3[(long long)i * 32 + j] * a[j] + c[j];
    atomicAdd(&pooled[g * 32 + j], v);
}

// ---------------------------------------------------------------------------
// Per-graph MLP: 32 -> 128 relu -> 64 relu -> 2. One block per graph.
// ---------------------------------------------------------------------------
__global__ void __launch_bounds__(128) k_mlp(
    const float* __restrict__ pooled,
    const float* __restrict__ Wf1, const float* __restrict__ bf1,
    const float* __restrict__ Wf2, const float* __restrict__ bf2,
    const float* __restrict__ Wf3, const float* __restrict__ bf3,
    float* __restrict__ out)
{
    __shared__ float p[32], h1[128], h2[64];
    int g = blockIdx.x, t = threadIdx.x;
    if (t < 32) p[t] = pooled[g * 32 + t];
    __syncthreads();
    {
        float acc = bf1[t];
        #pragma unroll
        for (int k = 0; k < 32; k++) acc += p[k] * Wf1[k * 128 + t];
        h1[t] = fmaxf(acc, 0.f);
    }
    __syncthreads();
    if (t < 64) {
        float acc = bf2[t];
        #pragma unroll
        for (int k = 0; k < 128; k++) acc += h1[k] * Wf2[k * 64 + t];
        h2[t] = fmaxf(acc, 0.f);
    }
    __syncthreads();
    if (t < 2) {
        float acc = bf3[t];
        #pragma unroll
        for (int k = 0; k < 64; k++) acc += h2[k] * Wf3[k * 2 + t];
        out[g * 2 + t] = acc;
    }
}

// ---------------------------------------------------------------------------
extern "C" void kernel_launch(void* const* d_in, const int* in_sizes, int n_in,
                              void* d_out, int out_size, void* d_ws, size_t ws_size,
                              hipStream_t stream)
{
    const float* x     = (const float*)d_in[0];
    const int*   ei    = (const int*)d_in[1];
    const int*   batch = (const int*)d_in[2];
    const float* W1l = (const float*)d_in[3];
    const float* b1  = (const float*)d_in[4];
    const float* W1r = (const float*)d_in[5];
    const float* g1  = (const float*)d_in[6];
    const float* be1 = (const float*)d_in[7];
    const float* W2l = (const float*)d_in[8];
    const float* b2  = (const float*)d_in[9];
    const float* W2r = (const float*)d_in[10];
    const float* g2  = (const float*)d_in[11];
    const float* be2 = (const float*)d_in[12];
    const float* W3l = (const float*)d_in[13];
    const float* b3  = (const float*)d_in[14];
    const float* W3r = (const float*)d_in[15];
    const float* g3  = (const float*)d_in[16];
    const float* be3 = (const float*)d_in[17];
    const float* Wf1 = (const float*)d_in[18];
    const float* bf1 = (const float*)d_in[19];
    const float* Wf2 = (const float*)d_in[20];
    const float* bf2 = (const float*)d_in[21];
    const float* Wf3 = (const float*)d_in[22];
    const float* bf3 = (const float*)d_in[23];

    const int N = in_sizes[0] / 64;
    const int E = in_sizes[1] / 2;
    const int* src = ei;
    const int* dst = ei + E;

    // ---- workspace layout (with aliasing) ----
    char* ws = (char*)d_ws;
    size_t off = 0;
    auto alloc = [&](size_t bytes) {
        size_t o = off;
        off += (bytes + 511) & ~(size_t)511;
        return o;
    };
    const size_t o_rowoff = alloc((size_t)(N + 1) * 4);
    const size_t o_hist   = alloc((size_t)N * 4);
    const size_t o_cursor = alloc((size_t)N * 4);
    const size_t o_csr    = alloc((size_t)E * 4);
    const size_t o_agg1   = alloc((size_t)N * 64 * 4);   // agg1 -> m2 -> t2
    const size_t o_t1     = alloc((size_t)N * 128 * 4);  // y1 -> t1 (in place)
    const size_t o_y2     = alloc((size_t)N * 64 * 4);   // y2; then y3 | m3->t3
    const size_t o_pool   = alloc((size_t)NGRAPH * 32 * 4);
    const size_t o_stats  = alloc(448 * 4);
    const size_t o_aff    = alloc(448 * 4);
    (void)ws_size;

    int* row_off = (int*)(ws + o_rowoff);
    int* hist    = (int*)(ws + o_hist);
    int* cursor  = (int*)(ws + o_cursor);
    int* csr     = (int*)(ws + o_csr);
    float* agg1 = (float*)(ws + o_agg1);
    float* m2   = agg1;                       // alias (gather overwrites fully)
    float* t2   = m2;                         // in-place epilogue overwrite
    float* t1   = (float*)(ws + o_t1);        // y1 then t1 (in-place)
    float* y2   = (float*)(ws + o_y2);
    float* y3   = y2;                         // N x 32, y2 dead after gather
    float* m3   = y2 + (size_t)N * 32;
    float* t3   = m3;                         // in-place epilogue overwrite
    float* pooled = (float*)(ws + o_pool);
    float* s1 = (float*)(ws + o_stats);
    float* q1 = s1 + 128;
    float* s2 = q1 + 128;
    float* q2 = s2 + 64;
    float* s3 = q2 + 64;
    float* q3 = s3 + 32;
    float* a1 = (float*)(ws + o_aff);
    float* c1 = a1 + 128;
    float* a2 = c1 + 128;
    float* c2 = a2 + 64;
    float* a3 = c2 + 64;
    float* c3 = a3 + 32;

    const float invN = 1.0f / (float)N;
    const int GB = (N + 63) / 64;  // GEMM blocks (one 64-row tile each)

    // ---- zero accumulators ----
    hipMemsetAsync(ws + o_hist, 0, (size_t)N * 4, stream);
    hipMemsetAsync(ws + o_stats, 0, 448 * 4, stream);
    hipMemsetAsync(ws + o_pool, 0, (size_t)NGRAPH * 32 * 4, stream);

    // ---- CSR build (amortized over 3 aggregations) ----
    k_hist<<<2048, 256, 0, stream>>>(dst, hist, E);
    k_scan<<<1, 1024, 0, stream>>>(hist, row_off, cursor, N);
    k_scatter<<<2048, 256, 0, stream>>>(src, dst, cursor, csr, E);

    // ---- layer 1 ----
    k_gather<64><<<(N + 15) / 16, 256, 0, stream>>>(x, row_off, csr, agg1, N);
    // y1 = (agg1/cnt) @ W1l
    k_gemm<64, 128, false, true, false, false, false><<<GB, 256, 0, stream>>>(
        agg1, nullptr, nullptr, W1l, nullptr, nullptr, row_off, t1,
        nullptr, nullptr, N);
    // t1 = relu(x @ W1r + y1 + b1)  [in place over y1], stats
    k_gemm<64, 128, false, false, true, false, true><<<GB, 256, 0, stream>>>(
        x, nullptr, nullptr, W1r, b1, t1, row_off, t1, s1, q1, N);
    k_finalize<<<1, 128, 0, stream>>>(s1, q1, g1, be1, a1, c1, 128, invN);

    // ---- layer 2 (transform-first aggregation) ----
    // y2 = (t1*a1+c1) @ W2l
    k_gemm<128, 64, true, false, false, false, false><<<GB, 256, 0, stream>>>(
        t1, a1, c1, W2l, nullptr, nullptr, row_off, y2, nullptr, nullptr, N);
    k_gather<64><<<(N + 15) / 16, 256, 0, stream>>>(y2, row_off, csr, m2, N);
    // t2 = relu((t1*a1+c1) @ W2r + m2/cnt + b2)  [in place over m2], stats
    k_gemm<128, 64, true, false, true, true, true><<<GB, 256, 0, stream>>>(
        t1, a1, c1, W2r, b2, m2, row_off, t2, s2, q2, N);
    k_finalize<<<1, 64, 0, stream>>>(s2, q2, g2, be2, a2, c2, 64, invN);

    // ---- layer 3 ----
    k_gemm<64, 32, true, false, false, false, false><<<GB, 256, 0, stream>>>(
        t2, a2, c2, W3l, nullptr, nullptr, row_off, y3, nullptr, nullptr, N);
    k_gather<32><<<(N + 31) / 32, 256, 0, stream>>>(y3, row_off, csr, m3, N);
    k_gemm<64, 32, true, false, true, true, true><<<GB, 256, 0, stream>>>(
        t2, a2, c2, W3r, b3, m3, row_off, t3, s3, q3, N);
    k_finalize<<<1, 32, 0, stream>>>(s3, q3, g3, be3, a3, c3, 32, invN);

    // ---- pool + MLP ----
    {
        long long tot = (long long)N * 32;
        int blocks = (int)((tot + 255) / 256);
        k_pool<<<blocks, 256, 0, stream>>>(t3, a3, c3, batch, pooled, N);
    }
    k_mlp<<<NGRAPH, 128, 0, stream>>>(pooled, Wf1, bf1, Wf2, bf2, Wf3, bf3,
                                      (float*)d_out);
}